// Round 3
// baseline (872.726 us; speedup 1.0000x reference)
//
#include <hip/hip_runtime.h>

// Talking-heads attention, fully fused two-phase flash-style implementation.
// b=16, n=1024, dim=768, h=12, d=64.  All staged tensors fp16, MFMA 16x16x32 f16.
//
// Pipeline:
//  1. k_cast_x     : x (f32) -> xb (f16)
//  2. k_prep_w     : Wt = [Wq*SCALE | Wkv]^T (f16, N-major), WoT = Wo^T (f16)
//  3. k_gemm_qkv   : [q|k|v] = xb @ Wt, scattered to per-head [b][h][n][64] f16
//  4. k_transpose_v: vt[b][h][d][n] (so PV B-fragments are contiguous)
//  5. k_attn       : per (b, 32-row i-tile), see header comment at the kernel
//  6. k_gemm_out   : out = obuf @ WoT + bo (f32)
//
// Workspace layout (bytes), total 105,381,888:
//   xb   @ 0          (25,165,824)   -- reused as vt after gemm_qkv
//   Wt   @ 25165824   ( 3,538,944)
//   WoT  @ 28704768   ( 1,179,648)
//   qb   @ 29884416   (25,165,824)
//   kb   @ 55050240   (25,165,824)
//   vb   @ 80216064   (25,165,824)   -- reused as obuf after transpose

typedef _Float16 f16;
typedef _Float16 f16x8 __attribute__((ext_vector_type(8)));
typedef _Float16 f16x4 __attribute__((ext_vector_type(4)));
typedef float f32x4 __attribute__((ext_vector_type(4)));
typedef float fv4 __attribute__((ext_vector_type(4)));

#define MFMA(a, b, c) __builtin_amdgcn_mfma_f32_16x16x32_f16(a, b, c, 0, 0, 0)
#define MFMA16(a, b, c) __builtin_amdgcn_mfma_f32_16x16x16f16(a, b, c, 0, 0, 0)

// ---------------------------------------------------------------- cast x -> f16
__global__ __launch_bounds__(256) void k_cast_x(const float* __restrict__ x,
                                                f16* __restrict__ xb) {
  int idx = (blockIdx.x * 256 + threadIdx.x) * 8;
  fv4 a = *(const fv4*)(x + idx);
  fv4 b = *(const fv4*)(x + idx + 4);
  f16x8 o;
  o[0] = (f16)a[0]; o[1] = (f16)a[1]; o[2] = (f16)a[2]; o[3] = (f16)a[3];
  o[4] = (f16)b[0]; o[5] = (f16)b[1]; o[6] = (f16)b[2]; o[7] = (f16)b[3];
  *(f16x8*)(xb + idx) = o;
}

// ------------------------------------------- weights: transpose + cast (+scale q)
__global__ __launch_bounds__(256) void k_prep_w(const float* __restrict__ Wq,
                                                const float* __restrict__ Wkv,
                                                const float* __restrict__ Wo,
                                                f16* __restrict__ Wt,
                                                f16* __restrict__ WoT) {
  int idx = blockIdx.x * 256 + threadIdx.x;
  if (idx < 2304 * 768) {
    int n = idx / 768, k = idx % 768;
    float v = (n < 768) ? Wq[k * 768 + n] * 0.125f   // SCALE = 64^-0.5 folded here
                        : Wkv[k * 1536 + (n - 768)];
    Wt[idx] = (f16)v;
  } else {
    int id2 = idx - 2304 * 768;
    int n = id2 / 768, k = id2 % 768;
    WoT[id2] = (f16)Wo[k * 768 + n];
  }
}

// ---------------------------------------------------------------- QKV projection
__global__ __launch_bounds__(256) void k_gemm_qkv(const f16* __restrict__ A,
                                                  const f16* __restrict__ Bt,
                                                  f16* __restrict__ qb,
                                                  f16* __restrict__ kb,
                                                  f16* __restrict__ vb) {
  __shared__ f16 As[128 * 72];  // +8 pad: conflict-free b128 frag reads
  __shared__ f16 Bs[128 * 72];
  const int tid = threadIdx.x;
  const int m0 = blockIdx.y << 7;
  const int n0 = blockIdx.x << 7;
  const int lane = tid & 63, w = tid >> 6;
  const int quad = lane >> 4, col = lane & 15;
  const int wm = (w >> 1) << 6, wn = (w & 1) << 6;
  const f32x4 z4 = {0.f, 0.f, 0.f, 0.f};
  f32x4 acc[4][4];
#pragma unroll
  for (int i = 0; i < 4; ++i)
#pragma unroll
    for (int j = 0; j < 4; ++j) acc[i][j] = z4;

  for (int k0 = 0; k0 < 768; k0 += 64) {
#pragma unroll
    for (int s = 0; s < 4; ++s) {
      int u = s * 256 + tid;
      int row = u >> 3, seg = (u & 7) << 3;
      *(f16x8*)&As[row * 72 + seg] = *(const f16x8*)(A + (m0 + row) * 768 + k0 + seg);
      *(f16x8*)&Bs[row * 72 + seg] = *(const f16x8*)(Bt + (n0 + row) * 768 + k0 + seg);
    }
    __syncthreads();
#pragma unroll
    for (int kk = 0; kk < 64; kk += 32) {
      f16x8 af[4], bf[4];
#pragma unroll
      for (int ic = 0; ic < 4; ++ic)
        af[ic] = *(f16x8*)&As[(wm + ic * 16 + col) * 72 + kk + quad * 8];
#pragma unroll
      for (int jc = 0; jc < 4; ++jc)
        bf[jc] = *(f16x8*)&Bs[(wn + jc * 16 + col) * 72 + kk + quad * 8];
#pragma unroll
      for (int ic = 0; ic < 4; ++ic)
#pragma unroll
        for (int jc = 0; jc < 4; ++jc) acc[ic][jc] = MFMA(af[ic], bf[jc], acc[ic][jc]);
    }
    __syncthreads();
  }
  // epilogue: scatter to per-head q/k/v layouts
#pragma unroll
  for (int jc = 0; jc < 4; ++jc) {
    int gn = n0 + wn + jc * 16 + col;
#pragma unroll
    for (int ic = 0; ic < 4; ++ic)
#pragma unroll
      for (int r = 0; r < 4; ++r) {
        int gm = m0 + wm + ic * 16 + (quad << 2) + r;
        int b = gm >> 10, i = gm & 1023;
        f16 v = (f16)acc[ic][jc][r];
        if (gn < 768) {
          int h = gn >> 6, dd = gn & 63;
          qb[(((b * 12 + h) << 10) + i) * 64 + dd] = v;
        } else if (gn < 1536) {
          int t = gn - 768; int h = t >> 6, dd = t & 63;
          kb[(((b * 12 + h) << 10) + i) * 64 + dd] = v;
        } else {
          int t = gn - 1536; int h = t >> 6, dd = t & 63;
          vb[(((b * 12 + h) << 10) + i) * 64 + dd] = v;
        }
      }
  }
}

// ---------------------------------------------------------------- V transpose
__global__ __launch_bounds__(256) void k_transpose_v(const f16* __restrict__ vb,
                                                     f16* __restrict__ vt) {
  __shared__ f16 t[64 * 72];
  const int bh = blockIdx.x;        // 0..191
  const int n0 = blockIdx.y << 6;   // 16 tiles of 64
  const int tid = threadIdx.x;
#pragma unroll
  for (int s = 0; s < 2; ++s) {
    int u = s * 256 + tid;
    int r = u >> 3, c = (u & 7) << 3;
    *(f16x8*)&t[r * 72 + c] = *(const f16x8*)(vb + (bh * 1024 + n0 + r) * 64 + c);
  }
  __syncthreads();
#pragma unroll
  for (int s = 0; s < 2; ++s) {
    int u = s * 256 + tid;
    int d = u >> 3, c = (u & 7) << 3;
    f16x8 o;
#pragma unroll
    for (int e = 0; e < 8; ++e) o[e] = t[(c + e) * 72 + d];
    *(f16x8*)(vt + (bh * 64 + d) * 1024 + n0 + c) = o;
  }
}

// ---------------------------------------------------------------- fused attention v3
// block = 512 thr (8 waves) handles (b, 32 query rows i0..i0+31).  Grid 512.
// Wave w: i-half ih=w>>2 (16 rows), j-quarter jq=w&3 (16 j of each 64-j tile).
// Traffic rationale: i-tile 32 halves the K/vt re-read factor vs i-tile 16, and
// the XCD swizzle bid=((bid0&7)<<6)|(bid0>>3) puts all 32 blocks of one b on one
// XCD *concurrently* (1 block/CU, 32 CUs/XCD) so that b's ~4.5MB Q/K/vt working
// set stays L2-resident instead of streaming from Infinity Cache every iteration.
// Per 64-j iteration each wave computes ALL 12 heads for its (i-half, j-quarter):
//   QK^T (MFMA 16x16x32, Q in 96 VGPRs) -> S staged WAVE-LOCALLY in LDS as b64
//   units [j][hgrp][unit], swizzle unit=(i+j)&15: write/read at 4-access minimum.
//   pre-mix MFMA 16x16x16 -> d1: lane (g=q4+r, i=col, j=t).
//   MAXLESS softmax: phase 1 l_run[r]+=exp(d1[r]) per-lane, 0 barriers; merge l
//   across the 4 j-quarter waves of each i-half once.  phase 2: P=exp(d1)*il is
//   directly the A-fragment of post-mix MFMA16 (no LDS).  d2 buffered 4 j-tiles
//   in regs -> Pm[g'][i 32][64 j] (48KB) XOR-swizzled b64 units.
//   PV: 24 (g',i-half) units / 8 waves = 3 each; V from vt (L2).
// 2 barriers per 64-j iteration.  LDS = 64KB S + 48KB Pm = 112KB dynamic.
__global__ __launch_bounds__(512, 2) void k_attn(
    const f16* __restrict__ qb, const f16* __restrict__ kb, const f16* __restrict__ vt,
    const float* __restrict__ mixp, const float* __restrict__ mixq,
    f16* __restrict__ ob) {
  extern __shared__ f16 smem[];
  f16* Slds = smem;              // 8 waves x 4096 f16 (8KB each) = 64KB
  f16* Pmb  = smem + 8 * 4096;   // [g'][i 32][16 units][4] f16 = 48KB

  const int tid = threadIdx.x;
  const int bid0 = blockIdx.x;
  const int bid = ((bid0 & 7) << 6) | (bid0 >> 3);  // XCD chunk swizzle (bijective)
  const int b = bid >> 5;
  const int i0 = (bid & 31) << 5;
  const int lane = tid & 63;
  const int w = tid >> 6;
  const int quad = lane >> 4, col = lane & 15;
  const int q4 = quad << 2;
  const int ih = w >> 2;          // i-half (0/1): rows i0+ih*16 .. +15
  const int jq = w & 3;           // j-quarter within each 64-j tile
  const int jw = jq << 4;
  const f32x4 z4 = {0.f, 0.f, 0.f, 0.f};

  // mix fragments for 16x16x16: lane holds k-slots h = quad*4+e.
  // b_pre : A[m=g=col][k=h]   = mixp[h][g]   (mixp^T)
  // b_post: B[k=g][n=g'=col]  = mixq[g][g']
  f16x4 b_pre, b_post;
#pragma unroll
  for (int e = 0; e < 4; ++e) {
    int hk = q4 + e;
    bool ok = (hk < 12) && (col < 12);
    b_pre[e]  = ok ? (f16)mixp[hk * 12 + col] : (f16)0.f;
    b_post[e] = ok ? (f16)mixq[hk * 12 + col] : (f16)0.f;
  }

  f16* Sw = &Slds[w * 4096];
  // zero hgrp=3 units once (k-slots 12..15 of the pre-mix read as 0.0, never NaN)
  {
    f16x4 z; z[0] = (f16)0.f; z[1] = (f16)0.f; z[2] = (f16)0.f; z[3] = (f16)0.f;
#pragma unroll
    for (int u = 0; u < 4; ++u) {
      int idx = u * 64 + lane;
      *(f16x4*)&Sw[(((idx >> 4) << 6) + 48 + (idx & 15)) * 4] = z;
    }
  }

  // Q fragments in registers: A[m=i=col][k=kc*32+quad*8+e] per head (96 VGPR)
  f16x8 qf[12][2];
#pragma unroll
  for (int h = 0; h < 12; ++h)
#pragma unroll
    for (int kc = 0; kc < 2; ++kc)
      qf[h][kc] = *(const f16x8*)(qb + ((((b * 12 + h) << 10) + i0 + ih * 16 + col) << 6) +
                                  kc * 32 + quad * 8);

  // stage: QK^T for all 12 heads on this wave's 16 j's; S -> wave-local LDS units.
  // unit (j=col, i=q4+r, hgrp) at pos j*64 + hgrp*16 + ((i+j)&15), content h asc.
  auto stage = [&](int j0) {
#pragma unroll
    for (int hg = 0; hg < 3; ++hg) {
      f32x4 s4[4];
#pragma unroll
      for (int e = 0; e < 4; ++e) {
        int h = hg * 4 + e;
        const f16* kbase = kb + ((((b * 12 + h) << 10) + j0 + jw + col) << 6);
        f16x8 kf0 = *(const f16x8*)(kbase + quad * 8);
        f16x8 kf1 = *(const f16x8*)(kbase + 32 + quad * 8);
        f32x4 a = MFMA(qf[h][0], kf0, z4);
        s4[e] = MFMA(qf[h][1], kf1, a);
      }
#pragma unroll
      for (int r = 0; r < 4; ++r) {
        f16x4 p;
        p[0] = (f16)s4[0][r]; p[1] = (f16)s4[1][r];
        p[2] = (f16)s4[2][r]; p[3] = (f16)s4[3][r];
        *(f16x4*)&Sw[((col << 6) + hg * 16 + ((q4 + r + col) & 15)) * 4] = p;
      }
    }
  };

  // ---------------- phase 1: denominators l per (g,i), fully per-lane, 0 barriers
  float l_run[4] = {0.f, 0.f, 0.f, 0.f};
  for (int j0 = 0; j0 < 1024; j0 += 64) {
    stage(j0);
#pragma unroll
    for (int t = 0; t < 16; ++t) {
      f16x4 sB = *(const f16x4*)&Sw[((t << 6) + quad * 16 + ((col + t) & 15)) * 4];
      f32x4 d1 = MFMA16(b_pre, sB, z4);
#pragma unroll
      for (int r = 0; r < 4; ++r) l_run[r] += __expf(d1[r]);
    }
  }
  // merge partial l across the 4 j-quarter waves of this i-half
  float* Lb = (float*)Pmb;  // [w][g(16)][i(16)] overlay, phase-boundary only
#pragma unroll
  for (int r = 0; r < 4; ++r) Lb[w * 256 + (q4 + r) * 16 + col] = l_run[r];
  __syncthreads();
  float il[4];
#pragma unroll
  for (int r = 0; r < 4; ++r) {
    float s = 0.f;
#pragma unroll
    for (int jj = 0; jj < 4; ++jj) s += Lb[(ih * 4 + jj) * 256 + (q4 + r) * 16 + col];
    il[r] = 1.f / s;
  }
  __syncthreads();  // Lb region handed back to Pm

  // ---------------- phase 2: recompute d1, P, post-mix, PV
  f32x4 oa[3][4];
#pragma unroll
  for (int g = 0; g < 3; ++g)
#pragma unroll
    for (int dc = 0; dc < 4; ++dc) oa[g][dc] = z4;

  for (int j0 = 0; j0 < 1024; j0 += 64) {
    stage(j0);
#pragma unroll
    for (int tt = 0; tt < 4; ++tt) {  // 4 tiles per Pm flush
      f16x4 pk[4];
#pragma unroll
      for (int t4 = 0; t4 < 4; ++t4) {
        int t = tt * 4 + t4;
        f16x4 sB = *(const f16x4*)&Sw[((t << 6) + quad * 16 + ((col + t) & 15)) * 4];
        f32x4 d1 = MFMA16(b_pre, sB, z4);
        f16x4 pA;
#pragma unroll
        for (int r = 0; r < 4; ++r) pA[r] = (f16)(__expf(d1[r]) * il[r]);
        f32x4 d2 = MFMA16(pA, b_post, z4);  // lane: (i=q4+r, g'=col, j=t)
#pragma unroll
        for (int r = 0; r < 4; ++r) pk[r][t4] = (f16)d2[r];
      }
      // flush unit (jq*4+tt) of row (g'=col, i=ih*16+q4+r), XOR-swizzled
      if (col < 12) {
#pragma unroll
        for (int r = 0; r < 4; ++r) {
          int iL = ih * 16 + q4 + r;
          int k4 = (col + iL) & 15;
          *(f16x4*)&Pmb[((col * 32 + iL) * 16 + (((jq << 2) + tt) ^ k4)) * 4] = pk[r];
        }
      }
    }
    __syncthreads();  // Pm complete (all 64 j from all 8 waves)
    // PV: wave w owns units 3w..3w+2 of the 24 (g', i-half) pairs
    __builtin_amdgcn_s_setprio(1);
#pragma unroll
    for (int gg = 0; gg < 3; ++gg) {
      int id = w * 3 + gg;
      int gp = id >> 1, ihp = id & 1;
      int row = gp * 32 + ihp * 16 + col;
      int k4r = (gp + ihp * 16 + col) & 15;
#pragma unroll
      for (int jh = 0; jh < 2; ++jh) {
        int ub = (jh * 4 + quad) * 2;
        f16x4 lo = *(const f16x4*)&Pmb[(row * 16 + (ub ^ k4r)) * 4];
        f16x4 hi = *(const f16x4*)&Pmb[(row * 16 + ((ub + 1) ^ k4r)) * 4];
        f16x8 aP = __builtin_shufflevector(lo, hi, 0, 1, 2, 3, 4, 5, 6, 7);
#pragma unroll
        for (int dc = 0; dc < 4; ++dc) {
          f16x8 vf = *(const f16x8*)(vt + ((((b * 12 + gp) << 6) + dc * 16 + col) << 10) +
                                     j0 + jh * 32 + quad * 8);
          oa[gg][dc] = MFMA(aP, vf, oa[gg][dc]);
        }
      }
    }
    __builtin_amdgcn_s_setprio(0);
    __syncthreads();  // Pm consumed before next iteration overwrites
  }

  // epilogue: O (C-layout: row=q4+r = i-local, col = d) -> obuf [b][n][768]
#pragma unroll
  for (int gg = 0; gg < 3; ++gg) {
    int id = w * 3 + gg;
    int gp = id >> 1, ihp = id & 1;
#pragma unroll
    for (int dc = 0; dc < 4; ++dc)
#pragma unroll
      for (int r = 0; r < 4; ++r)
        ob[((b << 10) + i0 + ihp * 16 + q4 + r) * 768 + gp * 64 + dc * 16 + col] =
            (f16)oa[gg][dc][r];
  }
}

// ---------------------------------------------------------------- output GEMM
__global__ __launch_bounds__(256) void k_gemm_out(const f16* __restrict__ A,
                                                  const f16* __restrict__ Bt,
                                                  const float* __restrict__ bias,
                                                  float* __restrict__ out) {
  __shared__ f16 As[128 * 72];
  __shared__ f16 Bs[128 * 72];
  const int tid = threadIdx.x;
  const int m0 = blockIdx.y << 7;
  const int n0 = blockIdx.x << 7;
  const int lane = tid & 63, w = tid >> 6;
  const int quad = lane >> 4, col = lane & 15;
  const int wm = (w >> 1) << 6, wn = (w & 1) << 6;
  const f32x4 z4 = {0.f, 0.f, 0.f, 0.f};
  f32x4 acc[4][4];
#pragma unroll
  for (int i = 0; i < 4; ++i)
#pragma unroll
    for (int j = 0; j < 4; ++j) acc[i][j] = z4;

  for (int k0 = 0; k0 < 768; k0 += 64) {
#pragma unroll
    for (int s = 0; s < 4; ++s) {
      int u = s * 256 + tid;
      int row = u >> 3, seg = (u & 7) << 3;
      *(f16x8*)&As[row * 72 + seg] = *(const f16x8*)(A + (m0 + row) * 768 + k0 + seg);
      *(f16x8*)&Bs[row * 72 + seg] = *(const f16x8*)(Bt + (n0 + row) * 768 + k0 + seg);
    }
    __syncthreads();
#pragma unroll
    for (int kk = 0; kk < 64; kk += 32) {
      f16x8 af[4], bf[4];
#pragma unroll
      for (int ic = 0; ic < 4; ++ic)
        af[ic] = *(f16x8*)&As[(wm + ic * 16 + col) * 72 + kk + quad * 8];
#pragma unroll
      for (int jc = 0; jc < 4; ++jc)
        bf[jc] = *(f16x8*)&Bs[(wn + jc * 16 + col) * 72 + kk + quad * 8];
#pragma unroll
      for (int ic = 0; ic < 4; ++ic)
#pragma unroll
        for (int jc = 0; jc < 4; ++jc) acc[ic][jc] = MFMA(af[ic], bf[jc], acc[ic][jc]);
    }
    __syncthreads();
  }
#pragma unroll
  for (int jc = 0; jc < 4; ++jc) {
    int gn = n0 + wn + jc * 16 + col;
    float bv = bias[gn];
#pragma unroll
    for (int ic = 0; ic < 4; ++ic)
#pragma unroll
      for (int r = 0; r < 4; ++r) {
        int gm = m0 + wm + ic * 16 + (quad << 2) + r;
        out[gm * 768 + gn] = acc[ic][jc][r] + bv;
      }
  }
}

// ---------------------------------------------------------------- launcher
extern "C" void kernel_launch(void* const* d_in, const int* in_sizes, int n_in,
                              void* d_out, int out_size, void* d_ws, size_t ws_size,
                              hipStream_t stream) {
  const float* x    = (const float*)d_in[0];
  const float* Wq   = (const float*)d_in[1];
  const float* Wkv  = (const float*)d_in[2];
  const float* mixp = (const float*)d_in[3];
  const float* mixq = (const float*)d_in[4];
  const float* Wo   = (const float*)d_in[5];
  const float* bo   = (const float*)d_in[6];
  float* out = (float*)d_out;

  char* ws = (char*)d_ws;
  f16* xb  = (f16*)(ws);
  f16* Wt  = (f16*)(ws + 25165824);
  f16* WoT = (f16*)(ws + 28704768);
  f16* qb  = (f16*)(ws + 29884416);
  f16* kb  = (f16*)(ws + 55050240);
  f16* vb  = (f16*)(ws + 80216064);
  f16* vt  = xb;   // xb dead after k_gemm_qkv
  f16* obuf = vb;  // vb dead after k_transpose_v

  k_cast_x<<<dim3(6144), dim3(256), 0, stream>>>(x, xb);
  k_prep_w<<<dim3(9216), dim3(256), 0, stream>>>(Wq, Wkv, Wo, Wt, WoT);
  k_gemm_qkv<<<dim3(18, 128), dim3(256), 0, stream>>>(xb, Wt, qb, kb, vb);
  k_transpose_v<<<dim3(192, 16), dim3(256), 0, stream>>>(vb, vt);
  k_attn<<<dim3(512), dim3(512), 114688, stream>>>(qb, kb, vt, mixp, mixq, obuf);
  k_gemm_out<<<dim3(6, 128), dim3(256), 0, stream>>>(obuf, WoT, bo, out);
}

// Round 4
// 770.290 us; speedup vs baseline: 1.1330x; 1.1330x over previous
//
#include <hip/hip_runtime.h>

// Talking-heads attention, fully fused two-phase flash-style implementation.
// b=16, n=1024, dim=768, h=12, d=64.  All staged tensors fp16, MFMA 16x16x32 f16.
//
// Pipeline:
//  1. k_cast_x     : x (f32) -> xb (f16)
//  2. k_prep_w     : Wt = [Wq*SCALE | Wkv]^T (f16, N-major), WoT = Wo^T (f16)
//  3. k_gemm_qkv   : [q|k|v] = xb @ Wt, scattered to per-head [b][h][n][64] f16
//  4. k_transpose_v: vt[b][h][d][n] (so PV B-fragments are contiguous)
//  5. k_attn       : per (b, 16-row i-tile), see header comment at the kernel
//  6. k_gemm_out   : out = obuf @ WoT + bo (f32)
//
// Workspace layout (bytes), total 105,381,888:
//   xb   @ 0          (25,165,824)   -- reused as vt after gemm_qkv
//   Wt   @ 25165824   ( 3,538,944)
//   WoT  @ 28704768   ( 1,179,648)
//   qb   @ 29884416   (25,165,824)
//   kb   @ 55050240   (25,165,824)
//   vb   @ 80216064   (25,165,824)   -- reused as obuf after transpose

typedef _Float16 f16;
typedef _Float16 f16x8 __attribute__((ext_vector_type(8)));
typedef _Float16 f16x4 __attribute__((ext_vector_type(4)));
typedef float f32x4 __attribute__((ext_vector_type(4)));
typedef float fv4 __attribute__((ext_vector_type(4)));

#define MFMA(a, b, c) __builtin_amdgcn_mfma_f32_16x16x32_f16(a, b, c, 0, 0, 0)
#define MFMA16(a, b, c) __builtin_amdgcn_mfma_f32_16x16x16f16(a, b, c, 0, 0, 0)

// ---------------------------------------------------------------- cast x -> f16
__global__ __launch_bounds__(256) void k_cast_x(const float* __restrict__ x,
                                                f16* __restrict__ xb) {
  int idx = (blockIdx.x * 256 + threadIdx.x) * 8;
  fv4 a = *(const fv4*)(x + idx);
  fv4 b = *(const fv4*)(x + idx + 4);
  f16x8 o;
  o[0] = (f16)a[0]; o[1] = (f16)a[1]; o[2] = (f16)a[2]; o[3] = (f16)a[3];
  o[4] = (f16)b[0]; o[5] = (f16)b[1]; o[6] = (f16)b[2]; o[7] = (f16)b[3];
  *(f16x8*)(xb + idx) = o;
}

// ------------------------------------------- weights: transpose + cast (+scale q)
__global__ __launch_bounds__(256) void k_prep_w(const float* __restrict__ Wq,
                                                const float* __restrict__ Wkv,
                                                const float* __restrict__ Wo,
                                                f16* __restrict__ Wt,
                                                f16* __restrict__ WoT) {
  int idx = blockIdx.x * 256 + threadIdx.x;
  if (idx < 2304 * 768) {
    int n = idx / 768, k = idx % 768;
    float v = (n < 768) ? Wq[k * 768 + n] * 0.125f   // SCALE = 64^-0.5 folded here
                        : Wkv[k * 1536 + (n - 768)];
    Wt[idx] = (f16)v;
  } else {
    int id2 = idx - 2304 * 768;
    int n = id2 / 768, k = id2 % 768;
    WoT[id2] = (f16)Wo[k * 768 + n];
  }
}

// ---------------------------------------------------------------- QKV projection
__global__ __launch_bounds__(256) void k_gemm_qkv(const f16* __restrict__ A,
                                                  const f16* __restrict__ Bt,
                                                  f16* __restrict__ qb,
                                                  f16* __restrict__ kb,
                                                  f16* __restrict__ vb) {
  __shared__ f16 As[128 * 72];  // +8 pad: conflict-free b128 frag reads
  __shared__ f16 Bs[128 * 72];
  const int tid = threadIdx.x;
  const int m0 = blockIdx.y << 7;
  const int n0 = blockIdx.x << 7;
  const int lane = tid & 63, w = tid >> 6;
  const int quad = lane >> 4, col = lane & 15;
  const int wm = (w >> 1) << 6, wn = (w & 1) << 6;
  const f32x4 z4 = {0.f, 0.f, 0.f, 0.f};
  f32x4 acc[4][4];
#pragma unroll
  for (int i = 0; i < 4; ++i)
#pragma unroll
    for (int j = 0; j < 4; ++j) acc[i][j] = z4;

  for (int k0 = 0; k0 < 768; k0 += 64) {
#pragma unroll
    for (int s = 0; s < 4; ++s) {
      int u = s * 256 + tid;
      int row = u >> 3, seg = (u & 7) << 3;
      *(f16x8*)&As[row * 72 + seg] = *(const f16x8*)(A + (m0 + row) * 768 + k0 + seg);
      *(f16x8*)&Bs[row * 72 + seg] = *(const f16x8*)(Bt + (n0 + row) * 768 + k0 + seg);
    }
    __syncthreads();
#pragma unroll
    for (int kk = 0; kk < 64; kk += 32) {
      f16x8 af[4], bf[4];
#pragma unroll
      for (int ic = 0; ic < 4; ++ic)
        af[ic] = *(f16x8*)&As[(wm + ic * 16 + col) * 72 + kk + quad * 8];
#pragma unroll
      for (int jc = 0; jc < 4; ++jc)
        bf[jc] = *(f16x8*)&Bs[(wn + jc * 16 + col) * 72 + kk + quad * 8];
#pragma unroll
      for (int ic = 0; ic < 4; ++ic)
#pragma unroll
        for (int jc = 0; jc < 4; ++jc) acc[ic][jc] = MFMA(af[ic], bf[jc], acc[ic][jc]);
    }
    __syncthreads();
  }
  // epilogue: scatter to per-head q/k/v layouts
#pragma unroll
  for (int jc = 0; jc < 4; ++jc) {
    int gn = n0 + wn + jc * 16 + col;
#pragma unroll
    for (int ic = 0; ic < 4; ++ic)
#pragma unroll
      for (int r = 0; r < 4; ++r) {
        int gm = m0 + wm + ic * 16 + (quad << 2) + r;
        int b = gm >> 10, i = gm & 1023;
        f16 v = (f16)acc[ic][jc][r];
        if (gn < 768) {
          int h = gn >> 6, dd = gn & 63;
          qb[(((b * 12 + h) << 10) + i) * 64 + dd] = v;
        } else if (gn < 1536) {
          int t = gn - 768; int h = t >> 6, dd = t & 63;
          kb[(((b * 12 + h) << 10) + i) * 64 + dd] = v;
        } else {
          int t = gn - 1536; int h = t >> 6, dd = t & 63;
          vb[(((b * 12 + h) << 10) + i) * 64 + dd] = v;
        }
      }
  }
}

// ---------------------------------------------------------------- V transpose
__global__ __launch_bounds__(256) void k_transpose_v(const f16* __restrict__ vb,
                                                     f16* __restrict__ vt) {
  __shared__ f16 t[64 * 72];
  const int bh = blockIdx.x;        // 0..191
  const int n0 = blockIdx.y << 6;   // 16 tiles of 64
  const int tid = threadIdx.x;
#pragma unroll
  for (int s = 0; s < 2; ++s) {
    int u = s * 256 + tid;
    int r = u >> 3, c = (u & 7) << 3;
    *(f16x8*)&t[r * 72 + c] = *(const f16x8*)(vb + (bh * 1024 + n0 + r) * 64 + c);
  }
  __syncthreads();
#pragma unroll
  for (int s = 0; s < 2; ++s) {
    int u = s * 256 + tid;
    int d = u >> 3, c = (u & 7) << 3;
    f16x8 o;
#pragma unroll
    for (int e = 0; e < 8; ++e) o[e] = t[(c + e) * 72 + d];
    *(f16x8*)(vt + (bh * 64 + d) * 1024 + n0 + c) = o;
  }
}

// ---------------------------------------------------------------- fused attention v4
// block = 256 thr (4 waves) handles (b, 16 query rows).  Wave w owns j-quarter
// jq=w (16 j of each 64-j tile) for ALL 12 heads.
// KEY CHANGE vs v2/v3: Q lives in LDS (24KB, XOR-swizzled 16B units), NOT in 96
// VGPRs.  v2/v3 allocated 128 VGPRs against ~170 live -> scratch spills inside
// the QK^T chain (WRITE_SIZE showed ~14MB of spill stores) and zero spare regs
// for K-load ILP.  Q-in-LDS frees ~96 VGPRs: no spills, compiler can keep many
// K loads in flight.  S staging shrinks to 3 hgrps + shared 128B zero block
// (quad-3 lanes of the pre-mix B-frag read zeros there): LDS = 24+25+24 = 73KB
// -> 2 blocks/CU.
//   QK^T (MFMA 16x16x32) -> S in wave-local LDS b64 units, swizzle (i+j)&15
//   (write/read at the 4-access b64 floor).  pre-mix MFMA 16x16x16 -> d1: lane
//   (g=q4+r, i=col, j=t).  MAXLESS softmax: phase 1 l+=exp(d1) per-lane, no
//   barriers; one cross-wave merge.  phase 2: P=exp(d1)*il is directly the
//   A-frag of the post-mix MFMA16 (no LDS); d2 buffered 4 j-tiles in regs ->
//   Pm[g'][i][64 j] XOR-swizzled; PV: wave w accumulates heads 3w..3w+2 from
//   vt (L2).  2 barriers per 64-j iteration.
__global__ __launch_bounds__(256, 2) void k_attn(
    const f16* __restrict__ qb, const f16* __restrict__ kb, const f16* __restrict__ vt,
    const float* __restrict__ mixp, const float* __restrict__ mixq,
    f16* __restrict__ ob) {
  extern __shared__ f16 smem[];
  f16* Qs   = smem;            // [12][16][64] f16, 16B-unit XOR swizzle (24KB)
  f16* Slds = smem + 12288;    // 4 waves x 3200 f16: [16 j][3 hgrp][16 u][4] + zeros
  f16* Pmb  = smem + 25088;    // [g'][i][16 units][4] f16 (24KB)

  const int tid = threadIdx.x;
  const int bid0 = blockIdx.x;
  const int bid = ((bid0 & 7) << 7) | (bid0 >> 3);  // XCD chunk swizzle (bijective)
  const int b = bid >> 6;
  const int i0 = (bid & 63) << 4;
  const int lane = tid & 63;
  const int w = tid >> 6;
  const int quad = lane >> 4, col = lane & 15;
  const int q4 = quad << 2;
  const int w3 = w * 3;
  const int jw = w << 4;  // wave's j offset within a 64-j iteration
  const f32x4 z4 = {0.f, 0.f, 0.f, 0.f};

  // mix fragments for 16x16x16: lane holds k-slots h = quad*4+e.
  // b_pre : A[m=g=col][k=h]   = mixp[h][g]   (mixp^T)
  // b_post: B[k=g][n=g'=col]  = mixq[g][g']
  f16x4 b_pre, b_post;
#pragma unroll
  for (int e = 0; e < 4; ++e) {
    int hk = q4 + e;
    bool ok = (hk < 12) && (col < 12);
    b_pre[e]  = ok ? (f16)mixp[hk * 12 + col] : (f16)0.f;
    b_post[e] = ok ? (f16)mixq[hk * 12 + col] : (f16)0.f;
  }

  f16* Sw = &Slds[w * 3200];
  // zero block at Sw[3072..3135]: pre-mix k-slots 12..15 (quad==3) read here
  if (lane < 16) {
    f16x4 z; z[0] = (f16)0.f; z[1] = (f16)0.f; z[2] = (f16)0.f; z[3] = (f16)0.f;
    *(f16x4*)&Sw[3072 + lane * 4] = z;
  }

  // stage Q tile -> Qs: Q[h][i][d], d in 8 units of 8 f16, unit stored at u^(i&7)
  // (b128 reads/writes then match the proven stride-72 conflict profile)
#pragma unroll
  for (int s = 0; s < 6; ++s) {
    int u = s * 256 + tid;                       // 0..1535
    int h = u >> 7, i = (u >> 3) & 15, uu = u & 7;
    f16x8 q = *(const f16x8*)(qb + ((((b * 12 + h) << 10) + i0 + i) << 6) + uu * 8);
    *(f16x8*)&Qs[(((h << 4) + i) << 6) + ((uu ^ (i & 7)) << 3)] = q;
  }
  __syncthreads();

  // stage: QK^T for all 12 heads on this wave's 16 j's; S -> wave-local LDS units.
  // unit (j=col, i=q4+r, hgrp) at Sw[j*192 + hg*64 + ((i+j)&15)*4], content h asc.
  auto stage = [&](int j0) {
#pragma unroll
    for (int hg = 0; hg < 3; ++hg) {
      f32x4 s4[4];
#pragma unroll
      for (int e = 0; e < 4; ++e) {
        int h = hg * 4 + e;
        const f16* kbase = kb + ((((b * 12 + h) << 10) + j0 + jw + col) << 6);
        f16x8 kf0 = *(const f16x8*)(kbase + quad * 8);
        f16x8 kf1 = *(const f16x8*)(kbase + 32 + quad * 8);
        f16x8 q0 = *(const f16x8*)&Qs[(((h << 4) + col) << 6) +
                                      ((quad ^ (col & 7)) << 3)];
        f16x8 q1 = *(const f16x8*)&Qs[(((h << 4) + col) << 6) +
                                      (((4 + quad) ^ (col & 7)) << 3)];
        f32x4 a = MFMA(q0, kf0, z4);
        s4[e] = MFMA(q1, kf1, a);
      }
#pragma unroll
      for (int r = 0; r < 4; ++r) {
        f16x4 p;
        p[0] = (f16)s4[0][r]; p[1] = (f16)s4[1][r];
        p[2] = (f16)s4[2][r]; p[3] = (f16)s4[3][r];
        *(f16x4*)&Sw[col * 192 + hg * 64 + ((q4 + r + col) & 15) * 4] = p;
      }
    }
  };
  // pre-mix B-frag read address: k-slot group = quad (hgrp), or zero block
  auto sread = [&](int t) -> f16x4 {
    int zi = (quad < 3) ? (t * 192 + quad * 64 + ((col + t) & 15) * 4)
                        : (3072 + ((col + t) & 15) * 4);
    return *(const f16x4*)&Sw[zi];
  };

  // ---------------- phase 1: denominators l per (g,i), fully per-lane, 0 barriers
  float l_run[4] = {0.f, 0.f, 0.f, 0.f};
  for (int j0 = 0; j0 < 1024; j0 += 64) {
    stage(j0);
#pragma unroll
    for (int t = 0; t < 16; ++t) {
      f16x4 sB = sread(t);
      f32x4 d1 = MFMA16(b_pre, sB, z4);
#pragma unroll
      for (int r = 0; r < 4; ++r) l_run[r] += __expf(d1[r]);
    }
  }
  // merge partial l across the 4 waves (disjoint j quarters)
  float* Lb = (float*)Pmb;  // [w][g(16)][i(16)] overlay, phase-boundary only
#pragma unroll
  for (int r = 0; r < 4; ++r) Lb[(w * 16 + q4 + r) * 16 + col] = l_run[r];
  __syncthreads();
  float il[4];
#pragma unroll
  for (int r = 0; r < 4; ++r) {
    float s = 0.f;
#pragma unroll
    for (int ww = 0; ww < 4; ++ww) s += Lb[(ww * 16 + q4 + r) * 16 + col];
    il[r] = 1.f / s;
  }
  __syncthreads();  // Lb region handed back to Pm

  // ---------------- phase 2: recompute d1, P, post-mix, PV
  f32x4 oa[3][4];
#pragma unroll
  for (int g = 0; g < 3; ++g)
#pragma unroll
    for (int dc = 0; dc < 4; ++dc) oa[g][dc] = z4;

  for (int j0 = 0; j0 < 1024; j0 += 64) {
    stage(j0);
#pragma unroll
    for (int tt = 0; tt < 4; ++tt) {  // 4 tiles per Pm flush
      f16x4 pk[4];
#pragma unroll
      for (int t4 = 0; t4 < 4; ++t4) {
        int t = tt * 4 + t4;
        f16x4 sB = sread(t);
        f32x4 d1 = MFMA16(b_pre, sB, z4);
        f16x4 pA;
#pragma unroll
        for (int r = 0; r < 4; ++r) pA[r] = (f16)(__expf(d1[r]) * il[r]);
        f32x4 d2 = MFMA16(pA, b_post, z4);  // lane: (i=q4+r, g'=col, j=t)
#pragma unroll
        for (int r = 0; r < 4; ++r) pk[r][t4] = (f16)d2[r];
      }
      // flush unit (w*4+tt) of row (g'=col, i=q4+r), XOR-swizzled
      if (col < 12) {
#pragma unroll
        for (int r = 0; r < 4; ++r) {
          int k4 = (col + q4 + r) & 15;
          *(f16x4*)&Pmb[(((col << 4) + q4 + r) * 16 + ((w * 4 + tt) ^ k4)) * 4] = pk[r];
        }
      }
    }
    __syncthreads();  // Pm complete (all 64 j from all waves)
    // PV: wave w owns heads 3w..3w+2; A = Pm fragments, B = vt (L2)
    __builtin_amdgcn_s_setprio(1);
#pragma unroll
    for (int gg = 0; gg < 3; ++gg) {
      int gp = w3 + gg;
      int k4r = (gp + col) & 15;
#pragma unroll
      for (int jh = 0; jh < 2; ++jh) {
        int ub = (jh * 4 + quad) * 2;
        f16x4 lo = *(const f16x4*)&Pmb[(((gp << 4) + col) * 16 + (ub ^ k4r)) * 4];
        f16x4 hi = *(const f16x4*)&Pmb[(((gp << 4) + col) * 16 + ((ub + 1) ^ k4r)) * 4];
        f16x8 aP = __builtin_shufflevector(lo, hi, 0, 1, 2, 3, 4, 5, 6, 7);
#pragma unroll
        for (int dc = 0; dc < 4; ++dc) {
          f16x8 vf = *(const f16x8*)(vt + ((((b * 12 + gp) << 6) + dc * 16 + col) << 10) +
                                     j0 + jh * 32 + quad * 8);
          oa[gg][dc] = MFMA(aP, vf, oa[gg][dc]);
        }
      }
    }
    __builtin_amdgcn_s_setprio(0);
    __syncthreads();  // Pm consumed before next iteration overwrites
  }

  // epilogue: O (C-layout: row=q4+r = i, col = d) -> obuf [b][n][768]
#pragma unroll
  for (int gg = 0; gg < 3; ++gg) {
    int gp = w3 + gg;
#pragma unroll
    for (int dc = 0; dc < 4; ++dc)
#pragma unroll
      for (int r = 0; r < 4; ++r)
        ob[((b << 10) + i0 + q4 + r) * 768 + gp * 64 + dc * 16 + col] =
            (f16)oa[gg][dc][r];
  }
}

// ---------------------------------------------------------------- output GEMM
__global__ __launch_bounds__(256) void k_gemm_out(const f16* __restrict__ A,
                                                  const f16* __restrict__ Bt,
                                                  const float* __restrict__ bias,
                                                  float* __restrict__ out) {
  __shared__ f16 As[128 * 72];
  __shared__ f16 Bs[128 * 72];
  const int tid = threadIdx.x;
  const int m0 = blockIdx.y << 7;
  const int n0 = blockIdx.x << 7;
  const int lane = tid & 63, w = tid >> 6;
  const int quad = lane >> 4, col = lane & 15;
  const int wm = (w >> 1) << 6, wn = (w & 1) << 6;
  const f32x4 z4 = {0.f, 0.f, 0.f, 0.f};
  f32x4 acc[4][4];
#pragma unroll
  for (int i = 0; i < 4; ++i)
#pragma unroll
    for (int j = 0; j < 4; ++j) acc[i][j] = z4;

  for (int k0 = 0; k0 < 768; k0 += 64) {
#pragma unroll
    for (int s = 0; s < 4; ++s) {
      int u = s * 256 + tid;
      int row = u >> 3, seg = (u & 7) << 3;
      *(f16x8*)&As[row * 72 + seg] = *(const f16x8*)(A + (m0 + row) * 768 + k0 + seg);
      *(f16x8*)&Bs[row * 72 + seg] = *(const f16x8*)(Bt + (n0 + row) * 768 + k0 + seg);
    }
    __syncthreads();
#pragma unroll
    for (int kk = 0; kk < 64; kk += 32) {
      f16x8 af[4], bf[4];
#pragma unroll
      for (int ic = 0; ic < 4; ++ic)
        af[ic] = *(f16x8*)&As[(wm + ic * 16 + col) * 72 + kk + quad * 8];
#pragma unroll
      for (int jc = 0; jc < 4; ++jc)
        bf[jc] = *(f16x8*)&Bs[(wn + jc * 16 + col) * 72 + kk + quad * 8];
#pragma unroll
      for (int ic = 0; ic < 4; ++ic)
#pragma unroll
        for (int jc = 0; jc < 4; ++jc) acc[ic][jc] = MFMA(af[ic], bf[jc], acc[ic][jc]);
    }
    __syncthreads();
  }
#pragma unroll
  for (int jc = 0; jc < 4; ++jc) {
    int gn = n0 + wn + jc * 16 + col;
    float bv = bias[gn];
#pragma unroll
    for (int ic = 0; ic < 4; ++ic)
#pragma unroll
      for (int r = 0; r < 4; ++r) {
        int gm = m0 + wm + ic * 16 + (quad << 2) + r;
        out[gm * 768 + gn] = acc[ic][jc][r] + bv;
      }
  }
}

// ---------------------------------------------------------------- launcher
extern "C" void kernel_launch(void* const* d_in, const int* in_sizes, int n_in,
                              void* d_out, int out_size, void* d_ws, size_t ws_size,
                              hipStream_t stream) {
  const float* x    = (const float*)d_in[0];
  const float* Wq   = (const float*)d_in[1];
  const float* Wkv  = (const float*)d_in[2];
  const float* mixp = (const float*)d_in[3];
  const float* mixq = (const float*)d_in[4];
  const float* Wo   = (const float*)d_in[5];
  const float* bo   = (const float*)d_in[6];
  float* out = (float*)d_out;

  char* ws = (char*)d_ws;
  f16* xb  = (f16*)(ws);
  f16* Wt  = (f16*)(ws + 25165824);
  f16* WoT = (f16*)(ws + 28704768);
  f16* qb  = (f16*)(ws + 29884416);
  f16* kb  = (f16*)(ws + 55050240);
  f16* vb  = (f16*)(ws + 80216064);
  f16* vt  = xb;   // xb dead after k_gemm_qkv
  f16* obuf = vb;  // vb dead after k_transpose_v

  k_cast_x<<<dim3(6144), dim3(256), 0, stream>>>(x, xb);
  k_prep_w<<<dim3(9216), dim3(256), 0, stream>>>(Wq, Wkv, Wo, Wt, WoT);
  k_gemm_qkv<<<dim3(18, 128), dim3(256), 0, stream>>>(xb, Wt, qb, kb, vb);
  k_transpose_v<<<dim3(192, 16), dim3(256), 0, stream>>>(vb, vt);
  k_attn<<<dim3(1024), dim3(256), 74752, stream>>>(qb, kb, vt, mixp, mixq, obuf);
  k_gemm_out<<<dim3(6, 128), dim3(256), 0, stream>>>(obuf, WoT, bo, out);
}